// Round 3
// baseline (220.518 us; speedup 1.0000x reference)
//
#include <hip/hip_runtime.h>
#include <stdint.h>
#include <math.h>

#define NPTS 4096      // N
#define NF 512         // feature dim
#define NBINS 16
#define BSZ 256        // bin size
#define TOPK 16
#define NBATCH 2
#define KSPLIT 4
#define SPART (NBATCH * NBINS * BSZ * BSZ)   // 2,097,152 floats per K-quarter

typedef float vf4 __attribute__((ext_vector_type(4)));   // clang-native for nontemporal builtins

// ---------- kernel 1: LSH bin assignment (one wave per point) ----------
__global__ __launch_bounds__(256) void k_assign(const float* __restrict__ x,
                                                const float* __restrict__ cb,
                                                int* __restrict__ bin_idx) {
    int gw   = (blockIdx.x * 256 + threadIdx.x) >> 6;   // point id 0..8191
    int lane = threadIdx.x & 63;
    const float* row = x + (size_t)gw * NF;
    float acc[8];
#pragma unroll
    for (int j = 0; j < 8; j++) acc[j] = 0.f;
    for (int f = lane; f < NF; f += 64) {
        float xv = row[f];
        const float4* c = (const float4*)(cb + f * 16);
        float4 c0 = c[0], c1 = c[1];
        acc[0] += xv * c0.x; acc[1] += xv * c0.y; acc[2] += xv * c0.z; acc[3] += xv * c0.w;
        acc[4] += xv * c1.x; acc[5] += xv * c1.y; acc[6] += xv * c1.z; acc[7] += xv * c1.w;
    }
#pragma unroll
    for (int off = 32; off > 0; off >>= 1) {
#pragma unroll
        for (int j = 0; j < 8; j++) acc[j] += __shfl_xor(acc[j], off, 64);
    }
    if (lane == 0) {
        // argmax over [mul0..mul7, -mul0..-mul7], first max wins (strict >)
        float best = acc[0]; int bi = 0;
#pragma unroll
        for (int j = 1; j < 8; j++) { if (acc[j] > best) { best = acc[j]; bi = j; } }
#pragma unroll
        for (int j = 0; j < 8; j++) { float v = -acc[j]; if (v > best) { best = v; bi = 8 + j; } }
        bin_idx[gw] = bi;
    }
}

// ---------- kernel 2: stable counting sort (one block per batch) ----------
__global__ __launch_bounds__(256) void k_sort(const int* __restrict__ bin_idx,
                                              int* __restrict__ order) {
    __shared__ int hist[NBINS][256];
    __shared__ int segsum[NBINS][16];
    __shared__ int segoff[NBINS][16];
    __shared__ int totals[NBINS];
    __shared__ int keybase[NBINS];
    int b = blockIdx.x, t = threadIdx.x;
    const int* bi = bin_idx + b * NPTS;
#pragma unroll
    for (int j = 0; j < NBINS; j++) hist[j][t] = 0;
    int base = t * 16;
    for (int i = 0; i < 16; i++) { int k = bi[base + i]; hist[k][t]++; }
    __syncthreads();
    { // per-key segment sums (16 segments of 16 threads each)
        int j = t >> 4, sg = t & 15, s = 0;
#pragma unroll
        for (int u = 0; u < 16; u++) s += hist[j][sg * 16 + u];
        segsum[j][sg] = s;
    }
    __syncthreads();
    if (t < NBINS) {
        int run = 0;
#pragma unroll
        for (int sg = 0; sg < 16; sg++) { int c = segsum[t][sg]; segoff[t][sg] = run; run += c; }
        totals[t] = run;
    }
    __syncthreads();
    if (t == 0) {
        int run = 0;
#pragma unroll
        for (int j = 0; j < NBINS; j++) { keybase[j] = run; run += totals[j]; }
    }
    __syncthreads();
    { // exclusive scan within segment -> hist[j][t] = within-key offset of thread t
        int j = t >> 4, sg = t & 15;
        int run = segoff[j][sg];
#pragma unroll
        for (int u = 0; u < 16; u++) { int c = hist[j][sg * 16 + u]; hist[j][sg * 16 + u] = run; run += c; }
    }
    __syncthreads();
    int* ob = order + b * NPTS;
    for (int i = 0; i < 16; i++) {   // in-order placement => stable
        int k = bi[base + i];
        int o = hist[k][t];
        hist[k][t] = o + 1;
        ob[keybase[k] + o] = base + i;
    }
}

// ---------- kernel 3: per-bin Gram matrix, fp32, 128x128 tile, K split x4 ----------
// grid 512 = kh(4) x tn(2) x tm(2) x bin(16) x b(2); S partials at out[0..4*SPART)
// 2 blocks/CU (34 KB LDS x2, VGPR<=256 via launch_bounds) -> 2 waves/SIMD for latency hiding
__global__ __launch_bounds__(256, 2) void k_gemm(const float* __restrict__ x,
                                                 const int* __restrict__ order,
                                                 float* __restrict__ S) {
    int blk = blockIdx.x;
    int kh  = blk & 3;
    int tn  = (blk >> 2) & 1;
    int tm  = (blk >> 3) & 1;
    int bin = (blk >> 4) & 15;
    int b   = blk >> 8;
    int t  = threadIdx.x;
    int tx = t & 15, ty = t >> 4;
    __shared__ int   idxA[128];
    __shared__ int   idxB[128];
    __shared__ float Asl[32][132];   // k-major, padded
    __shared__ float Bsl[32][132];
    int ob = b * NPTS + bin * BSZ;
    if (t < 128) idxA[t] = order[ob + tm * 128 + t];
    else         idxB[t - 128] = order[ob + tn * 128 + (t - 128)];
    __syncthreads();
    const float* xb = x + (size_t)b * (NPTS * NF);
    int rowi = t & 127;
    int qb   = t >> 7;   // 0 or 1: which interleaved quad set this thread loads
    const float* rowA = xb + (size_t)idxA[rowi] * NF + kh * 128;
    const float* rowB = xb + (size_t)idxB[rowi] * NF + kh * 128;
    float acc[8][8];
#pragma unroll
    for (int i = 0; i < 8; i++)
#pragma unroll
        for (int j = 0; j < 8; j++) acc[i][j] = 0.f;
    float4 pa[4], pb[4];
#pragma unroll
    for (int l = 0; l < 4; l++) {
        pa[l] = *(const float4*)(rowA + (qb + 2 * l) * 4);
        pb[l] = *(const float4*)(rowB + (qb + 2 * l) * 4);
    }
    for (int it = 0; it < 4; it++) {
        __syncthreads();
#pragma unroll
        for (int l = 0; l < 4; l++) {
            int kq = (qb + 2 * l) * 4;
            Asl[kq + 0][rowi] = pa[l].x; Asl[kq + 1][rowi] = pa[l].y;
            Asl[kq + 2][rowi] = pa[l].z; Asl[kq + 3][rowi] = pa[l].w;
            Bsl[kq + 0][rowi] = pb[l].x; Bsl[kq + 1][rowi] = pb[l].y;
            Bsl[kq + 2][rowi] = pb[l].z; Bsl[kq + 3][rowi] = pb[l].w;
        }
        __syncthreads();
        if (it < 3) {  // prefetch next K-chunk; latency hides under compute
            const float* a2 = rowA + (it + 1) * 32;
            const float* b2 = rowB + (it + 1) * 32;
#pragma unroll
            for (int l = 0; l < 4; l++) {
                pa[l] = *(const float4*)(a2 + (qb + 2 * l) * 4);
                pb[l] = *(const float4*)(b2 + (qb + 2 * l) * 4);
            }
        }
#pragma unroll
        for (int kk = 0; kk < 32; kk++) {
            float4 a0 = *(const float4*)&Asl[kk][ty * 8];
            float4 a1 = *(const float4*)&Asl[kk][ty * 8 + 4];
            float4 b0 = *(const float4*)&Bsl[kk][tx * 8];
            float4 b1 = *(const float4*)&Bsl[kk][tx * 8 + 4];
            float av[8] = {a0.x, a0.y, a0.z, a0.w, a1.x, a1.y, a1.z, a1.w};
            float bv[8] = {b0.x, b0.y, b0.z, b0.w, b1.x, b1.y, b1.z, b1.w};
#pragma unroll
            for (int i = 0; i < 8; i++)
#pragma unroll
                for (int j = 0; j < 8; j++) acc[i][j] += av[i] * bv[j];
        }
    }
    float* Sp = S + (size_t)kh * SPART;
    size_t rowbase = (size_t)(b * NBINS + bin) * BSZ;
#pragma unroll
    for (int i = 0; i < 8; i++) {
        int r = tm * 128 + ty * 8 + i;
        float* orow = Sp + (rowbase + r) * BSZ + tn * 128 + tx * 8;
        *(float4*)(orow)     = make_float4(acc[i][0], acc[i][1], acc[i][2], acc[i][3]);
        *(float4*)(orow + 4) = make_float4(acc[i][4], acc[i][5], acc[i][6], acc[i][7]);
    }
}

// ---------- kernel 4: exact top-16 per row, (value desc, index asc) ----------
__global__ __launch_bounds__(256) void k_topk(const float* __restrict__ S,
                                              const int* __restrict__ order,
                                              int* __restrict__ cols,
                                              float* __restrict__ vals) {
    int row  = (blockIdx.x * 256 + threadIdx.x) >> 6;   // (b*16+bin)*256 + i
    int lane = threadIdx.x & 63;
    const float* s0 = S + (size_t)row * BSZ;
    unsigned long long key[4];
#pragma unroll
    for (int q = 0; q < 4; q++) {
        int j = lane + 64 * q;
        float d = s0[j] + s0[j + SPART] + s0[j + 2 * SPART] + s0[j + 3 * SPART];
        float v = 1.0f / (1.0f + expf(-d));      // sigmoid, saturates to 1.0f like ref
        key[q] = ((unsigned long long)__float_as_uint(v) << 32) | (unsigned)(255 - j);
    }
    int myj = 0; float myv = 0.f;
#pragma unroll
    for (int it = 0; it < TOPK; it++) {
        unsigned long long k = key[0];
        if (key[1] > k) k = key[1];
        if (key[2] > k) k = key[2];
        if (key[3] > k) k = key[3];
#pragma unroll
        for (int off = 32; off > 0; off >>= 1) {
            unsigned long long o = __shfl_xor(k, off, 64);
            if (o > k) k = o;
        }
        int jw = 255 - (int)(k & 0xFFull);
        if (lane == it) { myj = jw; myv = __uint_as_float((unsigned)(k >> 32)); }
        if ((jw & 63) == lane) {   // owner invalidates the winner
            int q = jw >> 6;
            if      (q == 0) key[0] = 0ull;
            else if (q == 1) key[1] = 0ull;
            else if (q == 2) key[2] = 0ull;
            else             key[3] = 0ull;
        }
    }
    if (lane < TOPK) {
        int b   = row >> 12;
        int bin = (row >> 8) & 15;
        int i   = row & 255;
        const int* obp = order + b * NPTS + bin * BSZ;
        int srcg = obp[i];
        int dstg = obp[myj];
        int o = (b * NPTS + srcg) * TOPK + lane;
        cols[o] = dstg;
        vals[o] = myv;
    }
}

// ---------- kernel 5: compose each output row in LDS, stream once to HBM ----------
__global__ __launch_bounds__(256) void k_write(const int* __restrict__ cols,
                                               const float* __restrict__ vals,
                                               float* __restrict__ out) {
    __shared__ float buf[NPTS];
    __shared__ int   pc[TOPK];
    __shared__ float pv[TOPK];
    int row = blockIdx.x;          // b*4096 + src
    int t   = threadIdx.x;
    if (t < TOPK) { pc[t] = cols[row * TOPK + t]; pv[t] = vals[row * TOPK + t]; }
    vf4 z = {0.f, 0.f, 0.f, 0.f};
#pragma unroll
    for (int u = 0; u < 4; u++) ((vf4*)buf)[u * 256 + t] = z;
    __syncthreads();               // LDS-only + 128B loads outstanding: cheap drain
    if (t < TOPK) buf[pc[t]] = pv[t];
    __syncthreads();
    vf4* orow = (vf4*)(out + (size_t)row * NPTS);
#pragma unroll
    for (int u = 0; u < 4; u++) {
        __builtin_nontemporal_store(((const vf4*)buf)[u * 256 + t], &orow[u * 256 + t]);
    }
}

extern "C" void kernel_launch(void* const* d_in, const int* in_sizes, int n_in,
                              void* d_out, int out_size, void* d_ws, size_t ws_size,
                              hipStream_t stream) {
    const float* x  = (const float*)d_in[0];
    const float* cb = (const float*)d_in[1];
    float* out = (float*)d_out;
    // workspace layout (1.1 MB total)
    int*   bin_idx = (int*)d_ws;
    int*   order   = bin_idx + NBATCH * NPTS;
    int*   cols    = order + NBATCH * NPTS;
    float* vals    = (float*)(cols + NBATCH * NPTS * TOPK);
    // S partials (4 x 8 MB) live in the head of d_out; k_write overwrites all of it
    float* S = out;

    k_assign<<<2048, 256, 0, stream>>>(x, cb, bin_idx);
    k_sort  <<<NBATCH, 256, 0, stream>>>(bin_idx, order);
    k_gemm  <<<512, 256, 0, stream>>>(x, order, S);
    k_topk  <<<2048, 256, 0, stream>>>(S, order, cols, vals);
    k_write <<<NBATCH * NPTS, 256, 0, stream>>>(cols, vals, out);
}

// Round 4
// 207.929 us; speedup vs baseline: 1.0605x; 1.0605x over previous
//
#include <hip/hip_runtime.h>
#include <stdint.h>
#include <math.h>

#define NPTS 4096      // N
#define NF 512         // feature dim
#define NBINS 16
#define BSZ 256        // bin size
#define TOPK 16
#define NBATCH 2
#define SPART (NBATCH * NBINS * BSZ * BSZ)   // 2,097,152 floats per K-quarter

typedef float vf4 __attribute__((ext_vector_type(4)));   // clang-native for nontemporal builtins

// ---------- kernel 1: LSH bin assignment (one wave per point) ----------
__global__ __launch_bounds__(256) void k_assign(const float* __restrict__ x,
                                                const float* __restrict__ cb,
                                                int* __restrict__ bin_idx) {
    int gw   = (blockIdx.x * 256 + threadIdx.x) >> 6;   // point id 0..8191
    int lane = threadIdx.x & 63;
    const float* row = x + (size_t)gw * NF;
    float acc[8];
#pragma unroll
    for (int j = 0; j < 8; j++) acc[j] = 0.f;
    for (int f = lane; f < NF; f += 64) {
        float xv = row[f];
        const float4* c = (const float4*)(cb + f * 16);
        float4 c0 = c[0], c1 = c[1];
        acc[0] += xv * c0.x; acc[1] += xv * c0.y; acc[2] += xv * c0.z; acc[3] += xv * c0.w;
        acc[4] += xv * c1.x; acc[5] += xv * c1.y; acc[6] += xv * c1.z; acc[7] += xv * c1.w;
    }
#pragma unroll
    for (int off = 32; off > 0; off >>= 1) {
#pragma unroll
        for (int j = 0; j < 8; j++) acc[j] += __shfl_xor(acc[j], off, 64);
    }
    if (lane == 0) {
        // argmax over [mul0..mul7, -mul0..-mul7], first max wins (strict >)
        float best = acc[0]; int bi = 0;
#pragma unroll
        for (int j = 1; j < 8; j++) { if (acc[j] > best) { best = acc[j]; bi = j; } }
#pragma unroll
        for (int j = 0; j < 8; j++) { float v = -acc[j]; if (v > best) { best = v; bi = 8 + j; } }
        bin_idx[gw] = bi;
    }
}

// ---------- kernel 2: stable counting sort (one block per batch) ----------
__global__ __launch_bounds__(256) void k_sort(const int* __restrict__ bin_idx,
                                              int* __restrict__ order) {
    __shared__ int hist[NBINS][256];
    __shared__ int segsum[NBINS][16];
    __shared__ int segoff[NBINS][16];
    __shared__ int totals[NBINS];
    __shared__ int keybase[NBINS];
    int b = blockIdx.x, t = threadIdx.x;
    const int* bi = bin_idx + b * NPTS;
#pragma unroll
    for (int j = 0; j < NBINS; j++) hist[j][t] = 0;
    int base = t * 16;
    for (int i = 0; i < 16; i++) { int k = bi[base + i]; hist[k][t]++; }
    __syncthreads();
    { // per-key segment sums (16 segments of 16 threads each)
        int j = t >> 4, sg = t & 15, s = 0;
#pragma unroll
        for (int u = 0; u < 16; u++) s += hist[j][sg * 16 + u];
        segsum[j][sg] = s;
    }
    __syncthreads();
    if (t < NBINS) {
        int run = 0;
#pragma unroll
        for (int sg = 0; sg < 16; sg++) { int c = segsum[t][sg]; segoff[t][sg] = run; run += c; }
        totals[t] = run;
    }
    __syncthreads();
    if (t == 0) {
        int run = 0;
#pragma unroll
        for (int j = 0; j < NBINS; j++) { keybase[j] = run; run += totals[j]; }
    }
    __syncthreads();
    { // exclusive scan within segment -> hist[j][t] = within-key offset of thread t
        int j = t >> 4, sg = t & 15;
        int run = segoff[j][sg];
#pragma unroll
        for (int u = 0; u < 16; u++) { int c = hist[j][sg * 16 + u]; hist[j][sg * 16 + u] = run; run += c; }
    }
    __syncthreads();
    int* ob = order + b * NPTS;
    for (int i = 0; i < 16; i++) {   // in-order placement => stable
        int k = bi[base + i];
        int o = hist[k][t];
        hist[k][t] = o + 1;
        ob[keybase[k] + o] = base + i;
    }
}

// ---------- kernel 3: per-bin Gram matrix, fp32, 128x128 tile, K split x4 ----------
// grid 512 = kh(4) x tn(2) x tm(2) x bin(16) x b(2); S partials in d_ws
__global__ __launch_bounds__(256, 2) void k_gemm(const float* __restrict__ x,
                                                 const int* __restrict__ order,
                                                 float* __restrict__ S) {
    int blk = blockIdx.x;
    int kh  = blk & 3;
    int tn  = (blk >> 2) & 1;
    int tm  = (blk >> 3) & 1;
    int bin = (blk >> 4) & 15;
    int b   = blk >> 8;
    int t  = threadIdx.x;
    int tx = t & 15, ty = t >> 4;
    __shared__ int   idxA[128];
    __shared__ int   idxB[128];
    __shared__ float Asl[32][132];   // k-major, padded
    __shared__ float Bsl[32][132];
    int ob = b * NPTS + bin * BSZ;
    if (t < 128) idxA[t] = order[ob + tm * 128 + t];
    else         idxB[t - 128] = order[ob + tn * 128 + (t - 128)];
    __syncthreads();
    const float* xb = x + (size_t)b * (NPTS * NF);
    int rowi = t & 127;
    int qb   = t >> 7;   // 0 or 1: which interleaved quad set this thread loads
    const float* rowA = xb + (size_t)idxA[rowi] * NF + kh * 128;
    const float* rowB = xb + (size_t)idxB[rowi] * NF + kh * 128;
    float acc[8][8];
#pragma unroll
    for (int i = 0; i < 8; i++)
#pragma unroll
        for (int j = 0; j < 8; j++) acc[i][j] = 0.f;
    float4 pa[4], pb[4];
#pragma unroll
    for (int l = 0; l < 4; l++) {
        pa[l] = *(const float4*)(rowA + (qb + 2 * l) * 4);
        pb[l] = *(const float4*)(rowB + (qb + 2 * l) * 4);
    }
    for (int it = 0; it < 4; it++) {
        __syncthreads();
#pragma unroll
        for (int l = 0; l < 4; l++) {
            int kq = (qb + 2 * l) * 4;
            Asl[kq + 0][rowi] = pa[l].x; Asl[kq + 1][rowi] = pa[l].y;
            Asl[kq + 2][rowi] = pa[l].z; Asl[kq + 3][rowi] = pa[l].w;
            Bsl[kq + 0][rowi] = pb[l].x; Bsl[kq + 1][rowi] = pb[l].y;
            Bsl[kq + 2][rowi] = pb[l].z; Bsl[kq + 3][rowi] = pb[l].w;
        }
        __syncthreads();
        if (it < 3) {  // prefetch next K-chunk; latency hides under compute
            const float* a2 = rowA + (it + 1) * 32;
            const float* b2 = rowB + (it + 1) * 32;
#pragma unroll
            for (int l = 0; l < 4; l++) {
                pa[l] = *(const float4*)(a2 + (qb + 2 * l) * 4);
                pb[l] = *(const float4*)(b2 + (qb + 2 * l) * 4);
            }
        }
#pragma unroll
        for (int kk = 0; kk < 32; kk++) {
            float4 a0 = *(const float4*)&Asl[kk][ty * 8];
            float4 a1 = *(const float4*)&Asl[kk][ty * 8 + 4];
            float4 b0 = *(const float4*)&Bsl[kk][tx * 8];
            float4 b1 = *(const float4*)&Bsl[kk][tx * 8 + 4];
            float av[8] = {a0.x, a0.y, a0.z, a0.w, a1.x, a1.y, a1.z, a1.w};
            float bv[8] = {b0.x, b0.y, b0.z, b0.w, b1.x, b1.y, b1.z, b1.w};
#pragma unroll
            for (int i = 0; i < 8; i++)
#pragma unroll
                for (int j = 0; j < 8; j++) acc[i][j] += av[i] * bv[j];
        }
    }
    float* Sp = S + (size_t)kh * SPART;
    size_t rowbase = (size_t)(b * NBINS + bin) * BSZ;
#pragma unroll
    for (int i = 0; i < 8; i++) {
        int r = tm * 128 + ty * 8 + i;
        float* orow = Sp + (rowbase + r) * BSZ + tn * 128 + tx * 8;
        *(float4*)(orow)     = make_float4(acc[i][0], acc[i][1], acc[i][2], acc[i][3]);
        *(float4*)(orow + 4) = make_float4(acc[i][4], acc[i][5], acc[i][6], acc[i][7]);
    }
}

// ---------- kernel 4: fused exact top-16 + output-row write (one wave per bin-row) ----------
// Every lane observes the uniform shuffle-max winner each iteration -> wj/wv captured with
// static indexing; the wave then composes its 16 KB output row in LDS and streams it out.
__global__ __launch_bounds__(64) void k_topkw(const float* __restrict__ S,
                                              const int* __restrict__ order,
                                              float* __restrict__ out) {
    __shared__ float buf[NPTS];
    int row  = blockIdx.x;            // (b*16+bin)*256 + i
    int lane = threadIdx.x;           // 0..63
    const float* s0 = S + (size_t)row * BSZ;
    unsigned long long key[4];
#pragma unroll
    for (int q = 0; q < 4; q++) {
        int j = lane + 64 * q;
        float d = s0[j] + s0[j + SPART] + s0[j + 2 * SPART] + s0[j + 3 * SPART];
        float v = 1.0f / (1.0f + expf(-d));      // sigmoid, saturates to 1.0f like ref
        key[q] = ((unsigned long long)__float_as_uint(v) << 32) | (unsigned)(255 - j);
    }
    int   wj[TOPK];
    float wv[TOPK];
#pragma unroll
    for (int it = 0; it < TOPK; it++) {
        unsigned long long k = key[0];
        if (key[1] > k) k = key[1];
        if (key[2] > k) k = key[2];
        if (key[3] > k) k = key[3];
#pragma unroll
        for (int off = 32; off > 0; off >>= 1) {
            unsigned long long o = __shfl_xor(k, off, 64);
            if (o > k) k = o;
        }
        int jw = 255 - (int)(k & 0xFFull);
        wj[it] = jw;                               // uniform across the wave
        wv[it] = __uint_as_float((unsigned)(k >> 32));
        if ((jw & 63) == lane) {   // owner invalidates the winner
            int q = jw >> 6;
            if      (q == 0) key[0] = 0ull;
            else if (q == 1) key[1] = 0ull;
            else if (q == 2) key[2] = 0ull;
            else             key[3] = 0ull;
        }
    }
    // zero the 16 KB row image in LDS
    vf4 z = {0.f, 0.f, 0.f, 0.f};
#pragma unroll
    for (int u = 0; u < 16; u++) ((vf4*)buf)[u * 64 + lane] = z;
    int b   = row >> 12;
    int bin = (row >> 8) & 15;
    int i   = row & 255;
    const int* obp = order + b * NPTS + bin * BSZ;
    int srcg = obp[i];                // uniform scalar load
    __syncthreads();
    // patch the 16 winners (lane `it` handles winner it; static reg indexing)
#pragma unroll
    for (int it = 0; it < TOPK; it++) {
        if (lane == it) buf[obp[wj[it]]] = wv[it];
    }
    __syncthreads();
    // stream the composed row to HBM, coalesced nontemporal float4
    vf4* orow = (vf4*)(out + ((size_t)b * NPTS + srcg) * NPTS);
#pragma unroll
    for (int u = 0; u < 16; u++) {
        __builtin_nontemporal_store(((const vf4*)buf)[u * 64 + lane], &orow[u * 64 + lane]);
    }
}

extern "C" void kernel_launch(void* const* d_in, const int* in_sizes, int n_in,
                              void* d_out, int out_size, void* d_ws, size_t ws_size,
                              hipStream_t stream) {
    const float* x  = (const float*)d_in[0];
    const float* cb = (const float*)d_in[1];
    float* out = (float*)d_out;
    // workspace layout (ws_size = 512 MiB per harness fill evidence; we use ~33.6 MB)
    int*   bin_idx = (int*)d_ws;                      // 8192 ints
    int*   order   = bin_idx + NBATCH * NPTS;         // 8192 ints
    float* S       = (float*)d_ws + 4 * NBATCH * NPTS; // 64 KB offset; 4*SPART floats = 33.5 MB

    k_assign<<<2048, 256, 0, stream>>>(x, cb, bin_idx);
    k_sort  <<<NBATCH, 256, 0, stream>>>(bin_idx, order);
    k_gemm  <<<512, 256, 0, stream>>>(x, order, S);
    k_topkw <<<NBATCH * NPTS * NBINS / 16, 64, 0, stream>>>(S, order, out);  // 8192 waves
}